// Round 10
// baseline (743.140 us; speedup 1.0000x reference)
//
#include <hip/hip_runtime.h>
#include <hip/hip_bf16.h>
#include <hip/hip_cooperative_groups.h>

namespace cg = cooperative_groups;

#define BB 2
#define CC 2
#define NN 1024
#define HH 8
#define FFV 64
#define BCHN (BB*CC*HH)          // 32
#define SVN  (BB*CC*HH*NN)       // 32768
#define NVB 1024                 // virtual blocks per phase

typedef _Float16 f16x8 __attribute__((ext_vector_type(8)));
typedef _Float16 f16x4 __attribute__((ext_vector_type(4)));
typedef __fp16 h16x2 __attribute__((ext_vector_type(2)));   // cvt_pkrtz native type
typedef float f32x4 __attribute__((ext_vector_type(4)));

struct GatParams {
  const float* x; const int* adj;
  const float* w1; const float* as1; const float* ad1;
  const float* w2; const float* as2; const float* ad2;
  _Float16* xh; _Float16* w1T; _Float16* w2T;
  unsigned long long* bmg;
  _Float16* HpT; _Float16* XB;
  float* s_v; float* d_v;
  float* out;
};

// ---------------- prep phase: convert x | transpose w1/w2 | build mask ----------------
__device__ __forceinline__ void prep_phase(int vb, int t, float* smem, const GatParams& p)
{
  if (vb < 256) {
    const int i = vb*256 + t;
    const float4 v = ((const float4*)p.x)[i];
    f16x4 o; o[0]=(_Float16)v.x; o[1]=(_Float16)v.y; o[2]=(_Float16)v.z; o[3]=(_Float16)v.w;
    ((f16x4*)p.xh)[i] = o;
  } else if (vb < 400) {
    _Float16* tile = (_Float16*)smem;   // 64*72 halfs
    int ch, k0, K; const float* w; _Float16* wT;
    if (vb < 272) { ch = vb - 256; k0 = 0; K = 64; w = p.w1; wT = p.w1T; }
    else { const int u = vb - 272; ch = u >> 3; k0 = (u & 7)*64; K = 512; w = p.w2; wT = p.w2T; }
    const float* src = w + ((size_t)ch*K + k0)*64;
    #pragma unroll
    for (int j = 0; j < 4; ++j) {
      const int u = t + j*256;
      const int k = u >> 4, seg = u & 15;
      const float4 v = ((const float4*)src)[(size_t)k*16 + seg];
      tile[(seg*4+0)*72 + k] = (_Float16)v.x;
      tile[(seg*4+1)*72 + k] = (_Float16)v.y;
      tile[(seg*4+2)*72 + k] = (_Float16)v.z;
      tile[(seg*4+3)*72 + k] = (_Float16)v.w;
    }
    __syncthreads();
    _Float16* dst = wT + (size_t)ch*64*K + k0;
    #pragma unroll
    for (int j = 0; j < 2; ++j) {
      const int u = t + j*256;
      const int f = u >> 3, seg = u & 7;
      const f16x8 o = *(const f16x8*)&tile[f*72 + seg*8];
      *(f16x8*)(dst + (size_t)f*K + seg*8) = o;
    }
  } else {
    const int wg = (vb - 400)*4 + (t >> 6);   // 624 blocks * 4 waves = 2496
    const int lane = t & 63;
    for (int idx = wg; idx < BB*NN*16; idx += 2496) {
      const int b = idx >> 14;
      const int n = (idx >> 4) & (NN - 1);
      const int word = idx & 15;
      const int m = word*64 + lane;
      const int pred = (p.adj[((size_t)b*NN + n)*NN + m] != 0) || (m == n);
      unsigned long long bits = __ballot(pred);
      if (lane == 0) p.bmg[idx] = bits;
    }
  }
  __syncthreads();
}

// ---------------- proj phase: C[32 rows][64 f] = A[rows][K] @ wT[f][K]^T ----------------
template<int K>
__device__ __forceinline__ void proj_phase(
    int vb, int t, float* smem,
    const _Float16* __restrict__ A, const _Float16* __restrict__ wT,
    const float* __restrict__ asrc, const float* __restrict__ adst,
    _Float16* __restrict__ HpT, float* __restrict__ s_out, float* __restrict__ d_out)
{
  float (*sp)[32] = (float (*)[32])smem;          // 4*32
  float (*sd)[32] = (float (*)[32])(smem + 128);  // 4*32
  const int bch = vb & 31;
  const int h = bch % HH; const int bc = bch / HH; const int c = bc % CC;
  const int row0 = (vb >> 5) * 32;
  const int w = t >> 6, lane = t & 63;
  const int colr = lane & 15, quad = lane >> 4;

  const _Float16* Arow0 = A + ((size_t)bc*NN + row0 + colr)*K;
  const _Float16* Arow1 = Arow0 + (size_t)16*K;
  const _Float16* Brow  = wT + ((size_t)(c*HH + h)*64 + w*16 + colr)*K;

  f32x4 acc0 = {0.f,0.f,0.f,0.f}, acc1 = {0.f,0.f,0.f,0.f};
  #pragma unroll 4
  for (int kb = 0; kb < K; kb += 32) {
    const f16x8 a0 = *(const f16x8*)(Arow0 + kb + quad*8);
    const f16x8 a1 = *(const f16x8*)(Arow1 + kb + quad*8);
    const f16x8 bf = *(const f16x8*)(Brow  + kb + quad*8);
    acc0 = __builtin_amdgcn_mfma_f32_16x16x32_f16(a0, bf, acc0, 0, 0, 0);
    acc1 = __builtin_amdgcn_mfma_f32_16x16x32_f16(a1, bf, acc1, 0, 0, 0);
  }

  const float af = asrc[(c*HH + h)*64 + w*16 + colr];
  const float bf_ = adst[(c*HH + h)*64 + w*16 + colr];
  _Float16* HT = HpT + ((size_t)bch*64 + w*16 + colr)*NN + row0;

  #pragma unroll
  for (int mt = 0; mt < 2; ++mt) {
    const f32x4 a = mt ? acc1 : acc0;
    f16x4 hv;
    #pragma unroll
    for (int i = 0; i < 4; ++i) {
      const float v = a[i];
      hv[i] = (_Float16)v;
      const float ex = __expf(2.f*v);
      const float th = 1.f - 2.f/(ex + 1.f);         // tanh(v)
      float ps = th * af, pd = th * bf_;
      #pragma unroll
      for (int off = 1; off < 16; off <<= 1) {
        ps += __shfl_xor(ps, off);
        pd += __shfl_xor(pd, off);
      }
      if (colr == 0) {
        sp[w][mt*16 + quad*4 + i] = ps;
        sd[w][mt*16 + quad*4 + i] = pd;
      }
    }
    *(f16x4*)(HT + mt*16 + quad*4) = hv;
  }
  __syncthreads();
  if (t < 32) {
    const float sv = sp[0][t] + sp[1][t] + sp[2][t] + sp[3][t];
    const float dv = sd[0][t] + sd[1][t] + sd[2][t] + sd[3][t];
    s_out[bch*NN + row0 + t] = sv;
    d_out[bch*NN + row0 + t] = dv;
  }
  __syncthreads();
}

// ---------------- attn phase (v4): 32-row tile, register P, global B-frags ----------------
template<int LAYER>
__device__ __forceinline__ void attn_phase(
    int vb, int t, float* smem,
    const _Float16* __restrict__ HpT, const float* __restrict__ s_arr,
    const float* __restrict__ d_arr, const unsigned long long* __restrict__ bmg,
    _Float16* __restrict__ outp)
{
  float* partials = smem;                              // 4 * 32*68
  float (*dsP)[32] = (float (*)[32])(smem + 4*32*68);  // 4*32
  const int bch = vb & 31;                   // vb%8 = bch%8 -> XCD-local HpT slice
  const int b = bch / (CC*HH);
  const int row0 = (vb >> 5) * 32;
  const int w = t >> 6, lane = t & 63;
  const int colr = lane & 15, quad = lane >> 4;

  // wave-local maxd over d[bch]
  const float* dg = d_arr + (size_t)bch*NN;
  const float4* dg4 = (const float4*)dg;
  float mxl = -1e30f;
  #pragma unroll
  for (int j = 0; j < 4; ++j) {
    const float4 v = dg4[lane + 64*j];
    mxl = fmaxf(fmaxf(v.x, v.y), fmaxf(fmaxf(v.z, v.w), mxl));
  }
  #pragma unroll
  for (int off = 1; off < 64; off <<= 1) mxl = fmaxf(mxl, __shfl_xor(mxl, off));
  const float maxd = mxl;

  const int r0 = row0 + colr, r1 = r0 + 16;
  const float s0 = s_arr[(size_t)bch*NN + r0];
  const float s1 = s_arr[(size_t)bch*NN + r1];
  const float so0 = s0 + maxd, so1 = s1 + maxd;
  const float offs0 = fmaxf(so0, 0.2f*so0);   // >= lrelu(s0+d) for all d
  const float offs1 = fmaxf(so1, 0.2f*so1);
  const float sA0 = s0 - offs0, sB0 = 0.2f*s0 - offs0;
  const float sA1 = s1 - offs1, sB1 = 0.2f*s1 - offs1;

  unsigned long long m0[4], m1[4];
  {
    const unsigned long long* bm0 = bmg + ((size_t)b*NN + r0)*16 + w*4;
    const unsigned long long* bm1 = bmg + ((size_t)b*NN + r1)*16 + w*4;
    #pragma unroll
    for (int j = 0; j < 4; ++j) { m0[j] = bm0[j]; m1[j] = bm1[j]; }
  }

  const _Float16* Bg = HpT + (size_t)bch*64*NN;
  const int kbase = w*256;
  const _Float16* Bp = Bg + kbase + quad*8;

  f32x4 acc[2][4], accs[2];
  #pragma unroll
  for (int rt = 0; rt < 2; ++rt) {
    accs[rt] = (f32x4){0.f,0.f,0.f,0.f};
    #pragma unroll
    for (int ft = 0; ft < 4; ++ft) acc[rt][ft] = (f32x4){0.f,0.f,0.f,0.f};
  }
  f16x8 ones;
  #pragma unroll
  for (int i = 0; i < 8; ++i) ones[i] = (_Float16)1.f;

  f16x8 Bc[4];
  #pragma unroll
  for (int ft = 0; ft < 4; ++ft) Bc[ft] = *(const f16x8*)(Bp + (size_t)(ft*16 + colr)*NN);
  float4 dc0 = *(const float4*)(dg + kbase + quad*8);
  float4 dc1 = *(const float4*)(dg + kbase + quad*8 + 4);

  #pragma unroll
  for (int ks = 0; ks < 8; ++ks) {
    f16x8 Bn[4]; float4 dn0, dn1;
    if (ks < 7) {
      #pragma unroll
      for (int ft = 0; ft < 4; ++ft)
        Bn[ft] = *(const f16x8*)(Bp + (size_t)(ft*16 + colr)*NN + (ks+1)*32);
      dn0 = *(const float4*)(dg + kbase + (ks+1)*32 + quad*8);
      dn1 = *(const float4*)(dg + kbase + (ks+1)*32 + quad*8 + 4);
    }
    const unsigned mb0 = (unsigned)((m0[ks >> 1] >> ((ks & 1)*32 + quad*8)) & 0xFFull);
    const unsigned mb1 = (unsigned)((m1[ks >> 1] >> ((ks & 1)*32 + quad*8)) & 0xFFull);
    const float dd[8] = {dc0.x, dc0.y, dc0.z, dc0.w, dc1.x, dc1.y, dc1.z, dc1.w};
    union { f16x8 v; h16x2 h[4]; } A0, A1;
    #pragma unroll
    for (int jp = 0; jp < 4; ++jp) {
      float p0[2], p1[2];
      #pragma unroll
      for (int jj = 0; jj < 2; ++jj) {
        const int j = jp*2 + jj;
        const float dj = dd[j];
        const float l0 = fmaxf(sA0 + dj, fmaf(0.2f, dj, sB0));
        const float l1 = fmaxf(sA1 + dj, fmaf(0.2f, dj, sB1));
        p0[jj] = ((mb0 >> j) & 1u) ? __expf(l0) : 0.f;
        p1[jj] = ((mb1 >> j) & 1u) ? __expf(l1) : 0.f;
      }
      A0.h[jp] = __builtin_amdgcn_cvt_pkrtz(p0[0], p0[1]);
      A1.h[jp] = __builtin_amdgcn_cvt_pkrtz(p1[0], p1[1]);
    }
    #pragma unroll
    for (int ft = 0; ft < 4; ++ft) {
      acc[0][ft] = __builtin_amdgcn_mfma_f32_16x16x32_f16(A0.v, Bc[ft], acc[0][ft], 0, 0, 0);
      acc[1][ft] = __builtin_amdgcn_mfma_f32_16x16x32_f16(A1.v, Bc[ft], acc[1][ft], 0, 0, 0);
    }
    accs[0] = __builtin_amdgcn_mfma_f32_16x16x32_f16(A0.v, ones, accs[0], 0, 0, 0);
    accs[1] = __builtin_amdgcn_mfma_f32_16x16x32_f16(A1.v, ones, accs[1], 0, 0, 0);
    if (ks < 7) {
      #pragma unroll
      for (int ft = 0; ft < 4; ++ft) Bc[ft] = Bn[ft];
      dc0 = dn0; dc1 = dn1;
    }
  }

  if (colr == 0) {
    #pragma unroll
    for (int i = 0; i < 4; ++i) {
      dsP[w][quad*4 + i] = accs[0][i];
      dsP[w][16 + quad*4 + i] = accs[1][i];
    }
  }
  float* pw = partials + w*(32*68);
  #pragma unroll
  for (int rt = 0; rt < 2; ++rt)
    #pragma unroll
    for (int ft = 0; ft < 4; ++ft)
      #pragma unroll
      for (int i = 0; i < 4; ++i)
        pw[(rt*16 + quad*4 + i)*68 + ft*16 + colr] = acc[rt][ft][i];
  __syncthreads();

  const int r = t >> 3, f0 = (t & 7)*8;
  const float dsum = dsP[0][r] + dsP[1][r] + dsP[2][r] + dsP[3][r];
  const float inv = 1.f / dsum;
  float4 c0 = {0.f,0.f,0.f,0.f}, c1 = {0.f,0.f,0.f,0.f};
  #pragma unroll
  for (int w4 = 0; w4 < 4; ++w4) {
    const float* base = &partials[w4*(32*68) + r*68 + f0];
    const float4 a0 = *(const float4*)base;
    const float4 a1 = *(const float4*)(base + 4);
    c0.x += a0.x; c0.y += a0.y; c0.z += a0.z; c0.w += a0.w;
    c1.x += a1.x; c1.y += a1.y; c1.z += a1.z; c1.w += a1.w;
  }
  const float cv[8] = {c0.x,c0.y,c0.z,c0.w, c1.x,c1.y,c1.z,c1.w};
  f16x8 o;
  #pragma unroll
  for (int i = 0; i < 8; ++i) {
    float v = cv[i] * inv;
    if (LAYER == 1) v = v > 0.f ? v : expm1f(v);
    o[i] = (_Float16)v;
  }
  const int bc = bch / HH, h = bch % HH;
  if (LAYER == 1)
    *(f16x8*)(outp + ((size_t)bc*NN + row0 + r)*512 + h*64 + f0) = o;
  else
    *(f16x8*)(outp + ((size_t)bch*NN + row0 + r)*64 + f0) = o;
  __syncthreads();
}

// ---------------- reduce phase: mean over heads -> fp32 ----------------
__device__ __forceinline__ void reduce_phase(int vb, int t, const GatParams& p)
{
  const int o = vb*256 + t;
  const int f = o & 63;
  const int n = (o >> 6) & (NN - 1);
  const int bc = o >> 16;
  float acc = 0.f;
  #pragma unroll
  for (int h = 0; h < HH; ++h)
    acc += (float)p.XB[(((size_t)bc*HH + h)*NN + n)*FFV + f];
  p.out[o] = acc * 0.125f;
}

// ---------------- Cooperative mega-kernel (any grid size via vb loops) ----------------
__global__ __launch_bounds__(256, 4) void gat_mega(GatParams p)
{
  __shared__ __align__(16) float smem[4*32*68 + 128];   // 35.3 KB
  const int t = threadIdx.x;
  const int nb = gridDim.x;
  cg::grid_group grid = cg::this_grid();

  for (int vb = blockIdx.x; vb < NVB; vb += nb) prep_phase(vb, t, smem, p);
  grid.sync();
  for (int vb = blockIdx.x; vb < NVB; vb += nb)
    proj_phase<64>(vb, t, smem, p.xh, p.w1T, p.as1, p.ad1, p.HpT, p.s_v, p.d_v);
  grid.sync();
  for (int vb = blockIdx.x; vb < NVB; vb += nb)
    attn_phase<1>(vb, t, smem, p.HpT, p.s_v, p.d_v, p.bmg, p.XB);
  grid.sync();
  for (int vb = blockIdx.x; vb < NVB; vb += nb)
    proj_phase<512>(vb, t, smem, p.XB, p.w2T, p.as2, p.ad2, p.HpT, p.s_v, p.d_v);
  grid.sync();
  for (int vb = blockIdx.x; vb < NVB; vb += nb)
    attn_phase<2>(vb, t, smem, p.HpT, p.s_v, p.d_v, p.bmg, p.XB);
  grid.sync();
  for (int vb = blockIdx.x; vb < NVB; vb += nb) reduce_phase(vb, t, p);
}

// ---------------- Fallback standalone kernels (R8-equivalent) ----------------
__global__ __launch_bounds__(256) void k_prep(GatParams p)
{
  __shared__ __align__(16) float smem[64*72/2 + 8];
  prep_phase(blockIdx.x, threadIdx.x, smem, p);
}
template<int K, int LAYER>
__global__ __launch_bounds__(256) void k_proj(GatParams p)
{
  __shared__ float smem[256];
  if (LAYER == 1)
    proj_phase<K>(blockIdx.x, threadIdx.x, smem, p.xh, p.w1T, p.as1, p.ad1, p.HpT, p.s_v, p.d_v);
  else
    proj_phase<K>(blockIdx.x, threadIdx.x, smem, p.XB, p.w2T, p.as2, p.ad2, p.HpT, p.s_v, p.d_v);
}
template<int LAYER>
__global__ __launch_bounds__(256, 4) void k_attn(GatParams p)
{
  __shared__ __align__(16) float smem[4*32*68 + 128];
  attn_phase<LAYER>(blockIdx.x, threadIdx.x, smem, p.HpT, p.s_v, p.d_v, p.bmg, p.XB);
}
__global__ __launch_bounds__(256) void k_reduce(GatParams p)
{
  reduce_phase(blockIdx.x, threadIdx.x, p);
}

extern "C" void kernel_launch(void* const* d_in, const int* in_sizes, int n_in,
                              void* d_out, int out_size, void* d_ws, size_t ws_size,
                              hipStream_t stream)
{
  char* w8 = (char*)d_ws;
  GatParams hp;
  hp.x   = (const float*)d_in[0];
  hp.adj = (const int*)d_in[1];
  hp.w1  = (const float*)d_in[2];
  hp.as1 = (const float*)d_in[3];
  hp.ad1 = (const float*)d_in[4];
  hp.w2  = (const float*)d_in[5];
  hp.as2 = (const float*)d_in[6];
  hp.ad2 = (const float*)d_in[7];
  hp.HpT = (_Float16*)(w8);                          // 4 MB  [bch][64][N]
  hp.XB  = (_Float16*)(w8 + (4u<<20));               // 4 MB  x1 then out2
  hp.xh  = (_Float16*)(w8 + (8u<<20));               // 512 KB
  hp.w1T = (_Float16*)(w8 + (8u<<20) + (512u<<10));  // 128 KB
  hp.w2T = (_Float16*)(w8 + (8u<<20) + (768u<<10));  // 1 MB
  hp.s_v = (float*)(w8 + (10u<<20));                 // 128 KB
  hp.d_v = (float*)(w8 + (10u<<20) + SVN*4);         // 128 KB
  hp.bmg = (unsigned long long*)(w8 + (10u<<20) + SVN*8);  // 256 KB
  hp.out = (float*)d_out;

  void* args[] = { &hp };
  // Try cooperative launch at decreasing grid sizes; vb loops make any size correct.
  hipError_t e = hipErrorUnknown;
  const int tries[3] = {1024, 768, 512};
  for (int i = 0; i < 3 && e != hipSuccess; ++i)
    e = hipLaunchCooperativeKernel((const void*)gat_mega, dim3(tries[i]), dim3(256),
                                   args, 0, stream);
  if (e != hipSuccess) {
    // Fallback: R8-equivalent multi-kernel pipeline (validated at 164.9 us).
    k_prep<<<NVB, 256, 0, stream>>>(hp);
    k_proj<64,1><<<NVB, 256, 0, stream>>>(hp);
    k_attn<1><<<NVB, 256, 0, stream>>>(hp);
    k_proj<512,2><<<NVB, 256, 0, stream>>>(hp);
    k_attn<2><<<NVB, 256, 0, stream>>>(hp);
    k_reduce<<<NVB, 256, 0, stream>>>(hp);
  }
}

// Round 11
// 293.759 us; speedup vs baseline: 2.5298x; 2.5298x over previous
//
#include <hip/hip_runtime.h>
#include <hip/hip_bf16.h>

#define BB 2
#define CC 2
#define NN 1024
#define HH 8
#define FFV 64
#define BCHN (BB*CC*HH)          // 32
#define SVN  (BB*CC*HH*NN)       // 32768

typedef _Float16 f16x8 __attribute__((ext_vector_type(8)));
typedef _Float16 f16x4 __attribute__((ext_vector_type(4)));
typedef __fp16 h16x2 __attribute__((ext_vector_type(2)));   // cvt_pkrtz native type
typedef float f32x4 __attribute__((ext_vector_type(4)));

// ---------------- prep: transpose w1/w2 -> f16 wT | build mask | zero counters ----------------
// grid 401: [0,16) w1T, [16,144) w2T, [144,400) mask, [400] zero cnt
__global__ __launch_bounds__(256) void prep_kernel(
    const int* __restrict__ adj, const float* __restrict__ w1, const float* __restrict__ w2,
    _Float16* __restrict__ w1T, _Float16* __restrict__ w2T,
    unsigned long long* __restrict__ bmg, int* __restrict__ cnt)
{
  __shared__ __align__(16) _Float16 tile[64*72];
  const int bx = blockIdx.x;
  const int t = threadIdx.x;
  if (bx < 144) {
    int ch, k0, K; const float* w; _Float16* wT;
    if (bx < 16) { ch = bx; k0 = 0; K = 64; w = w1; wT = w1T; }
    else { const int u = bx - 16; ch = u >> 3; k0 = (u & 7)*64; K = 512; w = w2; wT = w2T; }
    const float* src = w + ((size_t)ch*K + k0)*64;
    #pragma unroll
    for (int j = 0; j < 4; ++j) {
      const int u = t + j*256;
      const int k = u >> 4, seg = u & 15;
      const float4 v = ((const float4*)src)[(size_t)k*16 + seg];
      tile[(seg*4+0)*72 + k] = (_Float16)v.x;
      tile[(seg*4+1)*72 + k] = (_Float16)v.y;
      tile[(seg*4+2)*72 + k] = (_Float16)v.z;
      tile[(seg*4+3)*72 + k] = (_Float16)v.w;
    }
    __syncthreads();
    _Float16* dst = wT + (size_t)ch*64*K + k0;
    #pragma unroll
    for (int j = 0; j < 2; ++j) {
      const int u = t + j*256;
      const int f = u >> 3, seg = u & 7;
      const f16x8 o = *(const f16x8*)&tile[f*72 + seg*8];
      *(f16x8*)(dst + (size_t)f*K + seg*8) = o;
    }
  } else if (bx < 400) {
    const int wg = (bx - 144)*4 + (t >> 6);   // 256 blocks * 4 waves = 1024
    const int lane = t & 63;
    for (int idx = wg; idx < BB*NN*16; idx += 1024) {
      const int b = idx >> 14;
      const int n = (idx >> 4) & (NN - 1);
      const int word = idx & 15;
      const int m = word*64 + lane;
      const int pred = (adj[((size_t)b*NN + n)*NN + m] != 0) || (m == n);
      unsigned long long bits = __ballot(pred);
      if (lane == 0) bmg[idx] = bits;
    }
  } else {
    if (t < 128) cnt[t] = 0;
  }
}

// ---------------- Layer-1 projection (reads x fp32 directly): C[32r][64f] = x @ w1T^T ----------
__global__ __launch_bounds__(256) void proj1_mfma(
    const float* __restrict__ x,         // [bc][N][64] fp32
    const _Float16* __restrict__ wT,     // [c*HH+h][64][64]
    const float* __restrict__ asrc, const float* __restrict__ adst,
    _Float16* __restrict__ HpT, float* __restrict__ s_out, float* __restrict__ d_out)
{
  __shared__ float sp[4][32], sd[4][32];
  const int bch = blockIdx.y;
  const int h = bch % HH; const int bc = bch / HH; const int c = bc % CC;
  const int row0 = blockIdx.x*32;
  const int t = threadIdx.x;
  const int w = t >> 6, lane = t & 63;
  const int colr = lane & 15, quad = lane >> 4;

  const float* Ar0 = x + ((size_t)bc*NN + row0 + colr)*64;
  const float* Ar1 = Ar0 + (size_t)16*64;
  const _Float16* Brow = wT + ((size_t)(c*HH + h)*64 + w*16 + colr)*64;

  f32x4 acc0 = {0.f,0.f,0.f,0.f}, acc1 = {0.f,0.f,0.f,0.f};
  #pragma unroll
  for (int kb = 0; kb < 64; kb += 32) {
    const float4 u0 = *(const float4*)(Ar0 + kb + quad*8);
    const float4 u1 = *(const float4*)(Ar0 + kb + quad*8 + 4);
    const float4 v0 = *(const float4*)(Ar1 + kb + quad*8);
    const float4 v1 = *(const float4*)(Ar1 + kb + quad*8 + 4);
    union { f16x8 v; h16x2 h[4]; } a0, a1;
    a0.h[0] = __builtin_amdgcn_cvt_pkrtz(u0.x, u0.y);
    a0.h[1] = __builtin_amdgcn_cvt_pkrtz(u0.z, u0.w);
    a0.h[2] = __builtin_amdgcn_cvt_pkrtz(u1.x, u1.y);
    a0.h[3] = __builtin_amdgcn_cvt_pkrtz(u1.z, u1.w);
    a1.h[0] = __builtin_amdgcn_cvt_pkrtz(v0.x, v0.y);
    a1.h[1] = __builtin_amdgcn_cvt_pkrtz(v0.z, v0.w);
    a1.h[2] = __builtin_amdgcn_cvt_pkrtz(v1.x, v1.y);
    a1.h[3] = __builtin_amdgcn_cvt_pkrtz(v1.z, v1.w);
    const f16x8 bf = *(const f16x8*)(Brow + kb + quad*8);
    acc0 = __builtin_amdgcn_mfma_f32_16x16x32_f16(a0.v, bf, acc0, 0, 0, 0);
    acc1 = __builtin_amdgcn_mfma_f32_16x16x32_f16(a1.v, bf, acc1, 0, 0, 0);
  }

  const float af = asrc[(c*HH + h)*64 + w*16 + colr];
  const float bf_ = adst[(c*HH + h)*64 + w*16 + colr];
  _Float16* HT = HpT + ((size_t)bch*64 + w*16 + colr)*NN + row0;

  #pragma unroll
  for (int mt = 0; mt < 2; ++mt) {
    const f32x4 a = mt ? acc1 : acc0;
    f16x4 hv;
    #pragma unroll
    for (int i = 0; i < 4; ++i) {
      const float v = a[i];
      hv[i] = (_Float16)v;
      const float ex = __expf(2.f*v);
      const float th = 1.f - 2.f/(ex + 1.f);         // tanh(v)
      float ps = th * af, pd = th * bf_;
      #pragma unroll
      for (int off = 1; off < 16; off <<= 1) {
        ps += __shfl_xor(ps, off);
        pd += __shfl_xor(pd, off);
      }
      if (colr == 0) {
        sp[w][mt*16 + quad*4 + i] = ps;
        sd[w][mt*16 + quad*4 + i] = pd;
      }
    }
    *(f16x4*)(HT + mt*16 + quad*4) = hv;
  }
  __syncthreads();
  if (t < 32) {
    const float sv = sp[0][t] + sp[1][t] + sp[2][t] + sp[3][t];
    const float dv = sd[0][t] + sd[1][t] + sd[2][t] + sd[3][t];
    s_out[bch*NN + row0 + t] = sv;
    d_out[bch*NN + row0 + t] = dv;
  }
}

// ---------------- Layer-2 projection via MFMA (f16 A): R8 proj_mfma<512> verbatim ----------------
__global__ __launch_bounds__(256) void proj2_mfma(
    const _Float16* __restrict__ A,      // [bc][N][512]
    const _Float16* __restrict__ wT,     // [c*HH+h][64][512]
    const float* __restrict__ asrc, const float* __restrict__ adst,
    _Float16* __restrict__ HpT, float* __restrict__ s_out, float* __restrict__ d_out)
{
  const int K = 512;
  __shared__ float sp[4][32], sd[4][32];
  const int bch = blockIdx.y;
  const int h = bch % HH; const int bc = bch / HH; const int c = bc % CC;
  const int row0 = blockIdx.x*32;
  const int t = threadIdx.x;
  const int w = t >> 6, lane = t & 63;
  const int colr = lane & 15, quad = lane >> 4;

  const _Float16* Arow0 = A + ((size_t)bc*NN + row0 + colr)*K;
  const _Float16* Arow1 = Arow0 + (size_t)16*K;
  const _Float16* Brow  = wT + ((size_t)(c*HH + h)*64 + w*16 + colr)*K;

  f32x4 acc0 = {0.f,0.f,0.f,0.f}, acc1 = {0.f,0.f,0.f,0.f};
  #pragma unroll 4
  for (int kb = 0; kb < K; kb += 32) {
    const f16x8 a0 = *(const f16x8*)(Arow0 + kb + quad*8);
    const f16x8 a1 = *(const f16x8*)(Arow1 + kb + quad*8);
    const f16x8 bf = *(const f16x8*)(Brow  + kb + quad*8);
    acc0 = __builtin_amdgcn_mfma_f32_16x16x32_f16(a0, bf, acc0, 0, 0, 0);
    acc1 = __builtin_amdgcn_mfma_f32_16x16x32_f16(a1, bf, acc1, 0, 0, 0);
  }

  const float af = asrc[(c*HH + h)*64 + w*16 + colr];
  const float bf_ = adst[(c*HH + h)*64 + w*16 + colr];
  _Float16* HT = HpT + ((size_t)bch*64 + w*16 + colr)*NN + row0;

  #pragma unroll
  for (int mt = 0; mt < 2; ++mt) {
    const f32x4 a = mt ? acc1 : acc0;
    f16x4 hv;
    #pragma unroll
    for (int i = 0; i < 4; ++i) {
      const float v = a[i];
      hv[i] = (_Float16)v;
      const float ex = __expf(2.f*v);
      const float th = 1.f - 2.f/(ex + 1.f);
      float ps = th * af, pd = th * bf_;
      #pragma unroll
      for (int off = 1; off < 16; off <<= 1) {
        ps += __shfl_xor(ps, off);
        pd += __shfl_xor(pd, off);
      }
      if (colr == 0) {
        sp[w][mt*16 + quad*4 + i] = ps;
        sd[w][mt*16 + quad*4 + i] = pd;
      }
    }
    *(f16x4*)(HT + mt*16 + quad*4) = hv;
  }
  __syncthreads();
  if (t < 32) {
    const float sv = sp[0][t] + sp[1][t] + sp[2][t] + sp[3][t];
    const float dv = sd[0][t] + sd[1][t] + sd[2][t] + sd[3][t];
    s_out[bch*NN + row0 + t] = sv;
    d_out[bch*NN + row0 + t] = dv;
  }
}

// ---------------- Fused attention v4 (R8 verbatim) + optional fused head-mean (LAYER 2) ----------
// grid (x=bch=32, y=N/32=32) -> linear%8 = bch%8 = XCD; HpT slice stays L2-local.
template<int LAYER>
__global__ __launch_bounds__(256, 4) void attn_mfma(
    const _Float16* __restrict__ HpT, const float* __restrict__ s_arr,
    const float* __restrict__ d_arr, const unsigned long long* __restrict__ bmg,
    _Float16* __restrict__ outp, int* __restrict__ cnt, float* __restrict__ outF)
{
  __shared__ float partials[4][32*68];   // 34.8 KB, stride 68 (2-way bank alias = free)
  __shared__ float dsP[4][32];
  __shared__ int is_last;
  const int bch = blockIdx.x;
  const int b = bch / (CC*HH);
  const int row0 = blockIdx.y*32;
  const int t = threadIdx.x;
  const int w = t >> 6, lane = t & 63;
  const int colr = lane & 15, quad = lane >> 4;

  // wave-local maxd over d[bch]
  const float* dg = d_arr + (size_t)bch*NN;
  const float4* dg4 = (const float4*)dg;
  float mxl = -1e30f;
  #pragma unroll
  for (int j = 0; j < 4; ++j) {
    const float4 v = dg4[lane + 64*j];
    mxl = fmaxf(fmaxf(v.x, v.y), fmaxf(fmaxf(v.z, v.w), mxl));
  }
  #pragma unroll
  for (int off = 1; off < 64; off <<= 1) mxl = fmaxf(mxl, __shfl_xor(mxl, off));
  const float maxd = mxl;

  const int r0 = row0 + colr, r1 = r0 + 16;
  const float s0 = s_arr[(size_t)bch*NN + r0];
  const float s1 = s_arr[(size_t)bch*NN + r1];
  const float so0 = s0 + maxd, so1 = s1 + maxd;
  const float offs0 = fmaxf(so0, 0.2f*so0);   // >= lrelu(s0+d) for all d
  const float offs1 = fmaxf(so1, 0.2f*so1);
  const float sA0 = s0 - offs0, sB0 = 0.2f*s0 - offs0;
  const float sA1 = s1 - offs1, sB1 = 0.2f*s1 - offs1;

  unsigned long long m0[4], m1[4];
  {
    const unsigned long long* bm0 = bmg + ((size_t)b*NN + r0)*16 + w*4;
    const unsigned long long* bm1 = bmg + ((size_t)b*NN + r1)*16 + w*4;
    #pragma unroll
    for (int j = 0; j < 4; ++j) { m0[j] = bm0[j]; m1[j] = bm1[j]; }
  }

  const _Float16* Bg = HpT + (size_t)bch*64*NN;
  const int kbase = w*256;
  const _Float16* Bp = Bg + kbase + quad*8;

  f32x4 acc[2][4], accs[2];
  #pragma unroll
  for (int rt = 0; rt < 2; ++rt) {
    accs[rt] = (f32x4){0.f,0.f,0.f,0.f};
    #pragma unroll
    for (int ft = 0; ft < 4; ++ft) acc[rt][ft] = (f32x4){0.f,0.f,0.f,0.f};
  }
  f16x8 ones;
  #pragma unroll
  for (int i = 0; i < 8; ++i) ones[i] = (_Float16)1.f;

  f16x8 Bc[4];
  #pragma unroll
  for (int ft = 0; ft < 4; ++ft) Bc[ft] = *(const f16x8*)(Bp + (size_t)(ft*16 + colr)*NN);
  float4 dc0 = *(const float4*)(dg + kbase + quad*8);
  float4 dc1 = *(const float4*)(dg + kbase + quad*8 + 4);

  #pragma unroll
  for (int ks = 0; ks < 8; ++ks) {
    f16x8 Bn[4]; float4 dn0, dn1;
    if (ks < 7) {
      #pragma unroll
      for (int ft = 0; ft < 4; ++ft)
        Bn[ft] = *(const f16x8*)(Bp + (size_t)(ft*16 + colr)*NN + (ks+1)*32);
      dn0 = *(const float4*)(dg + kbase + (ks+1)*32 + quad*8);
      dn1 = *(const float4*)(dg + kbase + (ks+1)*32 + quad*8 + 4);
    }
    const unsigned mb0 = (unsigned)((m0[ks >> 1] >> ((ks & 1)*32 + quad*8)) & 0xFFull);
    const unsigned mb1 = (unsigned)((m1[ks >> 1] >> ((ks & 1)*32 + quad*8)) & 0xFFull);
    const float dd[8] = {dc0.x, dc0.y, dc0.z, dc0.w, dc1.x, dc1.y, dc1.z, dc1.w};
    union { f16x8 v; h16x2 h[4]; } A0, A1;
    #pragma unroll
    for (int jp = 0; jp < 4; ++jp) {
      float p0[2], p1[2];
      #pragma unroll
      for (int jj = 0; jj < 2; ++jj) {
        const int j = jp*2 + jj;
        const float dj = dd[j];
        const float l0 = fmaxf(sA0 + dj, fmaf(0.2f, dj, sB0));
        const float l1 = fmaxf(sA1 + dj, fmaf(0.2f, dj, sB1));
        p0[jj] = ((mb0 >> j) & 1u) ? __expf(l0) : 0.f;
        p1[jj] = ((mb1 >> j) & 1u) ? __expf(l1) : 0.f;
      }
      A0.h[jp] = __builtin_amdgcn_cvt_pkrtz(p0[0], p0[1]);
      A1.h[jp] = __builtin_amdgcn_cvt_pkrtz(p1[0], p1[1]);
    }
    #pragma unroll
    for (int ft = 0; ft < 4; ++ft) {
      acc[0][ft] = __builtin_amdgcn_mfma_f32_16x16x32_f16(A0.v, Bc[ft], acc[0][ft], 0, 0, 0);
      acc[1][ft] = __builtin_amdgcn_mfma_f32_16x16x32_f16(A1.v, Bc[ft], acc[1][ft], 0, 0, 0);
    }
    accs[0] = __builtin_amdgcn_mfma_f32_16x16x32_f16(A0.v, ones, accs[0], 0, 0, 0);
    accs[1] = __builtin_amdgcn_mfma_f32_16x16x32_f16(A1.v, ones, accs[1], 0, 0, 0);
    if (ks < 7) {
      #pragma unroll
      for (int ft = 0; ft < 4; ++ft) Bc[ft] = Bn[ft];
      dc0 = dn0; dc1 = dn1;
    }
  }

  if (colr == 0) {
    #pragma unroll
    for (int i = 0; i < 4; ++i) {
      dsP[w][quad*4 + i] = accs[0][i];
      dsP[w][16 + quad*4 + i] = accs[1][i];
    }
  }
  float* pw = partials[w];
  #pragma unroll
  for (int rt = 0; rt < 2; ++rt)
    #pragma unroll
    for (int ft = 0; ft < 4; ++ft)
      #pragma unroll
      for (int i = 0; i < 4; ++i)
        pw[(rt*16 + quad*4 + i)*68 + ft*16 + colr] = acc[rt][ft][i];
  __syncthreads();

  const int r = t >> 3, f0 = (t & 7)*8;
  const float dsum = dsP[0][r] + dsP[1][r] + dsP[2][r] + dsP[3][r];
  const float inv = 1.f / dsum;
  float4 c0 = {0.f,0.f,0.f,0.f}, c1 = {0.f,0.f,0.f,0.f};
  #pragma unroll
  for (int w4 = 0; w4 < 4; ++w4) {
    const float* base = &partials[w4][r*68 + f0];
    const float4 a0 = *(const float4*)base;
    const float4 a1 = *(const float4*)(base + 4);
    c0.x += a0.x; c0.y += a0.y; c0.z += a0.z; c0.w += a0.w;
    c1.x += a1.x; c1.y += a1.y; c1.z += a1.z; c1.w += a1.w;
  }
  const float cv[8] = {c0.x,c0.y,c0.z,c0.w, c1.x,c1.y,c1.z,c1.w};
  f16x8 o;
  #pragma unroll
  for (int i = 0; i < 8; ++i) {
    float v = cv[i] * inv;
    if (LAYER == 1) v = v > 0.f ? v : expm1f(v);
    o[i] = (_Float16)v;
  }
  const int bc = bch / HH, h = bch % HH;
  if (LAYER == 1) {
    *(f16x8*)(outp + ((size_t)bc*NN + row0 + r)*512 + h*64 + f0) = o;
  } else {
    *(f16x8*)(outp + ((size_t)bch*NN + row0 + r)*64 + f0) = o;
    // ---- fused head-mean: last of the 8 head-blocks for (bc,row-tile) reduces ----
    __threadfence();
    if (t == 0) {
      const int gid = bc*32 + (row0 >> 5);
      const int old = atomicAdd(&cnt[gid], 1);
      is_last = (old == 7);
    }
    __syncthreads();
    if (is_last) {
      __threadfence();
      float accm[8] = {0.f,0.f,0.f,0.f,0.f,0.f,0.f,0.f};
      #pragma unroll
      for (int hh = 0; hh < HH; ++hh) {
        const f16x8 v = *(const f16x8*)(outp + (((size_t)bc*HH + hh)*NN + row0 + r)*64 + f0);
        #pragma unroll
        for (int i = 0; i < 8; ++i) accm[i] += (float)v[i];
      }
      float4 o0, o1;
      o0.x = accm[0]*0.125f; o0.y = accm[1]*0.125f; o0.z = accm[2]*0.125f; o0.w = accm[3]*0.125f;
      o1.x = accm[4]*0.125f; o1.y = accm[5]*0.125f; o1.z = accm[6]*0.125f; o1.w = accm[7]*0.125f;
      float* dst = outF + ((size_t)bc*NN + row0 + r)*64 + f0;
      *(float4*)dst = o0;
      *(float4*)(dst + 4) = o1;
    }
  }
}

extern "C" void kernel_launch(void* const* d_in, const int* in_sizes, int n_in,
                              void* d_out, int out_size, void* d_ws, size_t ws_size,
                              hipStream_t stream)
{
  const float* x   = (const float*)d_in[0];
  const int*   adj = (const int*)d_in[1];
  const float* w1  = (const float*)d_in[2];
  const float* as1 = (const float*)d_in[3];
  const float* ad1 = (const float*)d_in[4];
  const float* w2  = (const float*)d_in[5];
  const float* as2 = (const float*)d_in[6];
  const float* ad2 = (const float*)d_in[7];

  char* w8 = (char*)d_ws;
  _Float16* HpT = (_Float16*)(w8);                         // 4 MB  [bch][64][N]
  _Float16* XB  = (_Float16*)(w8 + (4u<<20));              // 4 MB  x1 [bc][N][512] then out2 [bch][N][64]
  _Float16* w1T = (_Float16*)(w8 + (8u<<20));              // 128 KB [ch][64][64]
  _Float16* w2T = (_Float16*)(w8 + (8u<<20) + (256u<<10)); // 1 MB   [ch][64][512]
  float* s_v = (float*)(w8 + (10u<<20));                   // 128 KB
  float* d_v = (float*)(w8 + (10u<<20) + SVN*4);           // 128 KB
  unsigned long long* bmg = (unsigned long long*)(w8 + (10u<<20) + SVN*8);  // 256 KB
  int* cnt = (int*)(w8 + (10u<<20) + SVN*8 + (256u<<10));  // 512 B

  prep_kernel<<<401, 256, 0, stream>>>(adj, w1, w2, w1T, w2T, bmg, cnt);
  proj1_mfma<<<dim3(NN/32, BCHN), 256, 0, stream>>>(x, w1T, as1, ad1, HpT, s_v, d_v);
  attn_mfma<1><<<dim3(BCHN, NN/32), 256, 0, stream>>>(HpT, s_v, d_v, bmg, XB, cnt, (float*)d_out);
  proj2_mfma<<<dim3(NN/32, BCHN), 256, 0, stream>>>(XB, w2T, as2, ad2, HpT, s_v, d_v);
  attn_mfma<2><<<dim3(BCHN, NN/32), 256, 0, stream>>>(HpT, s_v, d_v, bmg, XB, cnt, (float*)d_out);
}

// Round 12
// 167.749 us; speedup vs baseline: 4.4301x; 1.7512x over previous
//
#include <hip/hip_runtime.h>
#include <hip/hip_bf16.h>

#define BB 2
#define CC 2
#define NN 1024
#define HH 8
#define FFV 64
#define BCHN (BB*CC*HH)          // 32
#define SVN  (BB*CC*HH*NN)       // 32768

typedef _Float16 f16x8 __attribute__((ext_vector_type(8)));
typedef _Float16 f16x4 __attribute__((ext_vector_type(4)));
typedef __fp16 h16x2 __attribute__((ext_vector_type(2)));   // cvt_pkrtz native type
typedef float f32x4 __attribute__((ext_vector_type(4)));

// ---------------- prep: transpose w1/w2 -> f16 wT | build mask ----------------
// grid 400: [0,16) w1T, [16,144) w2T, [144,400) mask
__global__ __launch_bounds__(256) void prep_kernel(
    const int* __restrict__ adj, const float* __restrict__ w1, const float* __restrict__ w2,
    _Float16* __restrict__ w1T, _Float16* __restrict__ w2T,
    unsigned long long* __restrict__ bmg)
{
  __shared__ __align__(16) _Float16 tile[64*72];
  const int bx = blockIdx.x;
  const int t = threadIdx.x;
  if (bx < 144) {
    int ch, k0, K; const float* w; _Float16* wT;
    if (bx < 16) { ch = bx; k0 = 0; K = 64; w = w1; wT = w1T; }
    else { const int u = bx - 16; ch = u >> 3; k0 = (u & 7)*64; K = 512; w = w2; wT = w2T; }
    const float* src = w + ((size_t)ch*K + k0)*64;
    #pragma unroll
    for (int j = 0; j < 4; ++j) {
      const int u = t + j*256;
      const int k = u >> 4, seg = u & 15;
      const float4 v = ((const float4*)src)[(size_t)k*16 + seg];
      tile[(seg*4+0)*72 + k] = (_Float16)v.x;
      tile[(seg*4+1)*72 + k] = (_Float16)v.y;
      tile[(seg*4+2)*72 + k] = (_Float16)v.z;
      tile[(seg*4+3)*72 + k] = (_Float16)v.w;
    }
    __syncthreads();
    _Float16* dst = wT + (size_t)ch*64*K + k0;
    #pragma unroll
    for (int j = 0; j < 2; ++j) {
      const int u = t + j*256;
      const int f = u >> 3, seg = u & 7;
      const f16x8 o = *(const f16x8*)&tile[f*72 + seg*8];
      *(f16x8*)(dst + (size_t)f*K + seg*8) = o;
    }
  } else {
    const int wg = (bx - 144)*4 + (t >> 6);   // 256 blocks * 4 waves = 1024
    const int lane = t & 63;
    for (int idx = wg; idx < BB*NN*16; idx += 1024) {
      const int b = idx >> 14;
      const int n = (idx >> 4) & (NN - 1);
      const int word = idx & 15;
      const int m = word*64 + lane;
      const int pred = (adj[((size_t)b*NN + n)*NN + m] != 0) || (m == n);
      unsigned long long bits = __ballot(pred);
      if (lane == 0) bmg[idx] = bits;
    }
  }
}

// ---------------- Layer-1 projection (reads x fp32 directly): C[32r][64f] = x @ w1T^T ----------
__global__ __launch_bounds__(256) void proj1_mfma(
    const float* __restrict__ x,         // [bc][N][64] fp32
    const _Float16* __restrict__ wT,     // [c*HH+h][64][64]
    const float* __restrict__ asrc, const float* __restrict__ adst,
    _Float16* __restrict__ HpT, float* __restrict__ s_out, float* __restrict__ d_out)
{
  __shared__ float sp[4][32], sd[4][32];
  const int bch = blockIdx.y;
  const int h = bch % HH; const int bc = bch / HH; const int c = bc % CC;
  const int row0 = blockIdx.x*32;
  const int t = threadIdx.x;
  const int w = t >> 6, lane = t & 63;
  const int colr = lane & 15, quad = lane >> 4;

  const float* Ar0 = x + ((size_t)bc*NN + row0 + colr)*64;
  const float* Ar1 = Ar0 + (size_t)16*64;
  const _Float16* Brow = wT + ((size_t)(c*HH + h)*64 + w*16 + colr)*64;

  f32x4 acc0 = {0.f,0.f,0.f,0.f}, acc1 = {0.f,0.f,0.f,0.f};
  #pragma unroll
  for (int kb = 0; kb < 64; kb += 32) {
    const float4 u0 = *(const float4*)(Ar0 + kb + quad*8);
    const float4 u1 = *(const float4*)(Ar0 + kb + quad*8 + 4);
    const float4 v0 = *(const float4*)(Ar1 + kb + quad*8);
    const float4 v1 = *(const float4*)(Ar1 + kb + quad*8 + 4);
    union { f16x8 v; h16x2 h[4]; } a0, a1;
    a0.h[0] = __builtin_amdgcn_cvt_pkrtz(u0.x, u0.y);
    a0.h[1] = __builtin_amdgcn_cvt_pkrtz(u0.z, u0.w);
    a0.h[2] = __builtin_amdgcn_cvt_pkrtz(u1.x, u1.y);
    a0.h[3] = __builtin_amdgcn_cvt_pkrtz(u1.z, u1.w);
    a1.h[0] = __builtin_amdgcn_cvt_pkrtz(v0.x, v0.y);
    a1.h[1] = __builtin_amdgcn_cvt_pkrtz(v0.z, v0.w);
    a1.h[2] = __builtin_amdgcn_cvt_pkrtz(v1.x, v1.y);
    a1.h[3] = __builtin_amdgcn_cvt_pkrtz(v1.z, v1.w);
    const f16x8 bf = *(const f16x8*)(Brow + kb + quad*8);
    acc0 = __builtin_amdgcn_mfma_f32_16x16x32_f16(a0.v, bf, acc0, 0, 0, 0);
    acc1 = __builtin_amdgcn_mfma_f32_16x16x32_f16(a1.v, bf, acc1, 0, 0, 0);
  }

  const float af = asrc[(c*HH + h)*64 + w*16 + colr];
  const float bf_ = adst[(c*HH + h)*64 + w*16 + colr];
  _Float16* HT = HpT + ((size_t)bch*64 + w*16 + colr)*NN + row0;

  #pragma unroll
  for (int mt = 0; mt < 2; ++mt) {
    const f32x4 a = mt ? acc1 : acc0;
    f16x4 hv;
    #pragma unroll
    for (int i = 0; i < 4; ++i) {
      const float v = a[i];
      hv[i] = (_Float16)v;
      const float ex = __expf(2.f*v);
      const float th = 1.f - 2.f/(ex + 1.f);         // tanh(v)
      float ps = th * af, pd = th * bf_;
      #pragma unroll
      for (int off = 1; off < 16; off <<= 1) {
        ps += __shfl_xor(ps, off);
        pd += __shfl_xor(pd, off);
      }
      if (colr == 0) {
        sp[w][mt*16 + quad*4 + i] = ps;
        sd[w][mt*16 + quad*4 + i] = pd;
      }
    }
    *(f16x4*)(HT + mt*16 + quad*4) = hv;
  }
  __syncthreads();
  if (t < 32) {
    const float sv = sp[0][t] + sp[1][t] + sp[2][t] + sp[3][t];
    const float dv = sd[0][t] + sd[1][t] + sd[2][t] + sd[3][t];
    s_out[bch*NN + row0 + t] = sv;
    d_out[bch*NN + row0 + t] = dv;
  }
}

// ---------------- Layer-2 projection via MFMA (f16 A) ----------------
__global__ __launch_bounds__(256) void proj2_mfma(
    const _Float16* __restrict__ A,      // [bc][N][512]
    const _Float16* __restrict__ wT,     // [c*HH+h][64][512]
    const float* __restrict__ asrc, const float* __restrict__ adst,
    _Float16* __restrict__ HpT, float* __restrict__ s_out, float* __restrict__ d_out)
{
  const int K = 512;
  __shared__ float sp[4][32], sd[4][32];
  const int bch = blockIdx.y;
  const int h = bch % HH; const int bc = bch / HH; const int c = bc % CC;
  const int row0 = blockIdx.x*32;
  const int t = threadIdx.x;
  const int w = t >> 6, lane = t & 63;
  const int colr = lane & 15, quad = lane >> 4;

  const _Float16* Arow0 = A + ((size_t)bc*NN + row0 + colr)*K;
  const _Float16* Arow1 = Arow0 + (size_t)16*K;
  const _Float16* Brow  = wT + ((size_t)(c*HH + h)*64 + w*16 + colr)*K;

  f32x4 acc0 = {0.f,0.f,0.f,0.f}, acc1 = {0.f,0.f,0.f,0.f};
  #pragma unroll 4
  for (int kb = 0; kb < K; kb += 32) {
    const f16x8 a0 = *(const f16x8*)(Arow0 + kb + quad*8);
    const f16x8 a1 = *(const f16x8*)(Arow1 + kb + quad*8);
    const f16x8 bf = *(const f16x8*)(Brow  + kb + quad*8);
    acc0 = __builtin_amdgcn_mfma_f32_16x16x32_f16(a0, bf, acc0, 0, 0, 0);
    acc1 = __builtin_amdgcn_mfma_f32_16x16x32_f16(a1, bf, acc1, 0, 0, 0);
  }

  const float af = asrc[(c*HH + h)*64 + w*16 + colr];
  const float bf_ = adst[(c*HH + h)*64 + w*16 + colr];
  _Float16* HT = HpT + ((size_t)bch*64 + w*16 + colr)*NN + row0;

  #pragma unroll
  for (int mt = 0; mt < 2; ++mt) {
    const f32x4 a = mt ? acc1 : acc0;
    f16x4 hv;
    #pragma unroll
    for (int i = 0; i < 4; ++i) {
      const float v = a[i];
      hv[i] = (_Float16)v;
      const float ex = __expf(2.f*v);
      const float th = 1.f - 2.f/(ex + 1.f);
      float ps = th * af, pd = th * bf_;
      #pragma unroll
      for (int off = 1; off < 16; off <<= 1) {
        ps += __shfl_xor(ps, off);
        pd += __shfl_xor(pd, off);
      }
      if (colr == 0) {
        sp[w][mt*16 + quad*4 + i] = ps;
        sd[w][mt*16 + quad*4 + i] = pd;
      }
    }
    *(f16x4*)(HT + mt*16 + quad*4) = hv;
  }
  __syncthreads();
  if (t < 32) {
    const float sv = sp[0][t] + sp[1][t] + sp[2][t] + sp[3][t];
    const float dv = sd[0][t] + sd[1][t] + sd[2][t] + sd[3][t];
    s_out[bch*NN + row0 + t] = sv;
    d_out[bch*NN + row0 + t] = dv;
  }
}

// ---------------- Fused attention v5: v4 + 3-buffer load pipeline (depth-2 coverage) ----------
// grid (x=bch=32, y=N/32=32) -> linear%8 = bch%8 = XCD; HpT slice stays L2-local.
template<int LAYER>
__global__ __launch_bounds__(256, 4) void attn_mfma(
    const _Float16* __restrict__ HpT, const float* __restrict__ s_arr,
    const float* __restrict__ d_arr, const unsigned long long* __restrict__ bmg,
    _Float16* __restrict__ outp)
{
  __shared__ float partials[4][32*68];   // 34.8 KB, stride 68 (2-way bank alias = free)
  __shared__ float dsP[4][32];
  const int bch = blockIdx.x;
  const int b = bch / (CC*HH);
  const int row0 = blockIdx.y*32;
  const int t = threadIdx.x;
  const int w = t >> 6, lane = t & 63;
  const int colr = lane & 15, quad = lane >> 4;

  // wave-local maxd over d[bch]
  const float* dg = d_arr + (size_t)bch*NN;
  const float4* dg4 = (const float4*)dg;
  float mxl = -1e30f;
  #pragma unroll
  for (int j = 0; j < 4; ++j) {
    const float4 v = dg4[lane + 64*j];
    mxl = fmaxf(fmaxf(v.x, v.y), fmaxf(fmaxf(v.z, v.w), mxl));
  }
  #pragma unroll
  for (int off = 1; off < 64; off <<= 1) mxl = fmaxf(mxl, __shfl_xor(mxl, off));
  const float maxd = mxl;

  const int r0 = row0 + colr, r1 = r0 + 16;
  const float s0 = s_arr[(size_t)bch*NN + r0];
  const float s1 = s_arr[(size_t)bch*NN + r1];
  const float so0 = s0 + maxd, so1 = s1 + maxd;
  const float offs0 = fmaxf(so0, 0.2f*so0);   // >= lrelu(s0+d) for all d
  const float offs1 = fmaxf(so1, 0.2f*so1);
  const float sA0 = s0 - offs0, sB0 = 0.2f*s0 - offs0;
  const float sA1 = s1 - offs1, sB1 = 0.2f*s1 - offs1;

  unsigned long long m0[4], m1[4];
  {
    const unsigned long long* bm0 = bmg + ((size_t)b*NN + r0)*16 + w*4;
    const unsigned long long* bm1 = bmg + ((size_t)b*NN + r1)*16 + w*4;
    #pragma unroll
    for (int j = 0; j < 4; ++j) { m0[j] = bm0[j]; m1[j] = bm1[j]; }
  }

  const _Float16* Bg = HpT + (size_t)bch*64*NN;
  const int kbase = w*256;
  const _Float16* Bp = Bg + kbase + quad*8;

  f32x4 acc[2][4], accs[2];
  #pragma unroll
  for (int rt = 0; rt < 2; ++rt) {
    accs[rt] = (f32x4){0.f,0.f,0.f,0.f};
    #pragma unroll
    for (int ft = 0; ft < 4; ++ft) acc[rt][ft] = (f32x4){0.f,0.f,0.f,0.f};
  }
  f16x8 ones;
  #pragma unroll
  for (int i = 0; i < 8; ++i) ones[i] = (_Float16)1.f;

  // 3-buffer pipeline: load for ks+2 issues BEFORE compute of ks
  f16x8 Bb[3][4];
  float4 db[3][2];
  #pragma unroll
  for (int j = 0; j < 2; ++j) {
    #pragma unroll
    for (int ft = 0; ft < 4; ++ft)
      Bb[j][ft] = *(const f16x8*)(Bp + (size_t)(ft*16 + colr)*NN + j*32);
    db[j][0] = *(const float4*)(dg + kbase + j*32 + quad*8);
    db[j][1] = *(const float4*)(dg + kbase + j*32 + quad*8 + 4);
  }

  #pragma unroll
  for (int ks = 0; ks < 8; ++ks) {
    const int cur = ks % 3;
    if (ks < 6) {
      const int nxt = (ks + 2) % 3;
      #pragma unroll
      for (int ft = 0; ft < 4; ++ft)
        Bb[nxt][ft] = *(const f16x8*)(Bp + (size_t)(ft*16 + colr)*NN + (ks+2)*32);
      db[nxt][0] = *(const float4*)(dg + kbase + (ks+2)*32 + quad*8);
      db[nxt][1] = *(const float4*)(dg + kbase + (ks+2)*32 + quad*8 + 4);
    }
    const unsigned mb0 = (unsigned)((m0[ks >> 1] >> ((ks & 1)*32 + quad*8)) & 0xFFull);
    const unsigned mb1 = (unsigned)((m1[ks >> 1] >> ((ks & 1)*32 + quad*8)) & 0xFFull);
    const float4 dc0 = db[cur][0], dc1 = db[cur][1];
    const float dd[8] = {dc0.x, dc0.y, dc0.z, dc0.w, dc1.x, dc1.y, dc1.z, dc1.w};
    union { f16x8 v; h16x2 h[4]; } A0, A1;
    #pragma unroll
    for (int jp = 0; jp < 4; ++jp) {
      float p0[2], p1[2];
      #pragma unroll
      for (int jj = 0; jj < 2; ++jj) {
        const int j = jp*2 + jj;
        const float dj = dd[j];
        const float l0 = fmaxf(sA0 + dj, fmaf(0.2f, dj, sB0));
        const float l1 = fmaxf(sA1 + dj, fmaf(0.2f, dj, sB1));
        p0[jj] = ((mb0 >> j) & 1u) ? __expf(l0) : 0.f;
        p1[jj] = ((mb1 >> j) & 1u) ? __expf(l1) : 0.f;
      }
      A0.h[jp] = __builtin_amdgcn_cvt_pkrtz(p0[0], p0[1]);
      A1.h[jp] = __builtin_amdgcn_cvt_pkrtz(p1[0], p1[1]);
    }
    #pragma unroll
    for (int ft = 0; ft < 4; ++ft) {
      acc[0][ft] = __builtin_amdgcn_mfma_f32_16x16x32_f16(A0.v, Bb[cur][ft], acc[0][ft], 0, 0, 0);
      acc[1][ft] = __builtin_amdgcn_mfma_f32_16x16x32_f16(A1.v, Bb[cur][ft], acc[1][ft], 0, 0, 0);
    }
    accs[0] = __builtin_amdgcn_mfma_f32_16x16x32_f16(A0.v, ones, accs[0], 0, 0, 0);
    accs[1] = __builtin_amdgcn_mfma_f32_16x16x32_f16(A1.v, ones, accs[1], 0, 0, 0);
  }

  if (colr == 0) {
    #pragma unroll
    for (int i = 0; i < 4; ++i) {
      dsP[w][quad*4 + i] = accs[0][i];
      dsP[w][16 + quad*4 + i] = accs[1][i];
    }
  }
  float* pw = partials[w];
  #pragma unroll
  for (int rt = 0; rt < 2; ++rt)
    #pragma unroll
    for (int ft = 0; ft < 4; ++ft)
      #pragma unroll
      for (int i = 0; i < 4; ++i)
        pw[(rt*16 + quad*4 + i)*68 + ft*16 + colr] = acc[rt][ft][i];
  __syncthreads();

  const int r = t >> 3, f0 = (t & 7)*8;
  const float dsum = dsP[0][r] + dsP[1][r] + dsP[2][r] + dsP[3][r];
  const float inv = 1.f / dsum;
  float4 c0 = {0.f,0.f,0.f,0.f}, c1 = {0.f,0.f,0.f,0.f};
  #pragma unroll
  for (int w4 = 0; w4 < 4; ++w4) {
    const float* base = &partials[w4][r*68 + f0];
    const float4 a0 = *(const float4*)base;
    const float4 a1 = *(const float4*)(base + 4);
    c0.x += a0.x; c0.y += a0.y; c0.z += a0.z; c0.w += a0.w;
    c1.x += a1.x; c1.y += a1.y; c1.z += a1.z; c1.w += a1.w;
  }
  const float cv[8] = {c0.x,c0.y,c0.z,c0.w, c1.x,c1.y,c1.z,c1.w};
  f16x8 o;
  #pragma unroll
  for (int i = 0; i < 8; ++i) {
    float v = cv[i] * inv;
    if (LAYER == 1) v = v > 0.f ? v : expm1f(v);
    o[i] = (_Float16)v;
  }
  const int bc = bch / HH, h = bch % HH;
  if (LAYER == 1)
    *(f16x8*)(outp + ((size_t)bc*NN + row0 + r)*512 + h*64 + f0) = o;
  else
    *(f16x8*)(outp + ((size_t)bch*NN + row0 + r)*64 + f0) = o;
}

// ---------------- Mean over heads (f16 in) -> fp32 out ----------------
__global__ __launch_bounds__(256) void reduce_heads(
    const _Float16* __restrict__ out2, float* __restrict__ out)
{
  const int o = blockIdx.x*256 + threadIdx.x;
  const int f = o & 63;
  const int n = (o >> 6) & (NN - 1);
  const int bc = o >> 16;
  float acc = 0.f;
  #pragma unroll
  for (int h = 0; h < HH; ++h)
    acc += (float)out2[(((size_t)bc*HH + h)*NN + n)*FFV + f];
  out[o] = acc * 0.125f;
}

extern "C" void kernel_launch(void* const* d_in, const int* in_sizes, int n_in,
                              void* d_out, int out_size, void* d_ws, size_t ws_size,
                              hipStream_t stream)
{
  const float* x   = (const float*)d_in[0];
  const int*   adj = (const int*)d_in[1];
  const float* w1  = (const float*)d_in[2];
  const float* as1 = (const float*)d_in[3];
  const float* ad1 = (const float*)d_in[4];
  const float* w2  = (const float*)d_in[5];
  const float* as2 = (const float*)d_in[6];
  const float* ad2 = (const float*)d_in[7];

  char* w8 = (char*)d_ws;
  _Float16* HpT = (_Float16*)(w8);                         // 4 MB  [bch][64][N]
  _Float16* XB  = (_Float16*)(w8 + (4u<<20));              // 4 MB  x1 [bc][N][512] then out2 [bch][N][64]
  _Float16* w1T = (_Float16*)(w8 + (8u<<20));              // 128 KB [ch][64][64]
  _Float16* w2T = (_Float16*)(w8 + (8u<<20) + (256u<<10)); // 1 MB   [ch][64][512]
  float* s_v = (float*)(w8 + (10u<<20));                   // 128 KB
  float* d_v = (float*)(w8 + (10u<<20) + SVN*4);           // 128 KB
  unsigned long long* bmg = (unsigned long long*)(w8 + (10u<<20) + SVN*8);  // 256 KB

  prep_kernel<<<400, 256, 0, stream>>>(adj, w1, w2, w1T, w2T, bmg);
  proj1_mfma<<<dim3(NN/32, BCHN), 256, 0, stream>>>(x, w1T, as1, ad1, HpT, s_v, d_v);
  attn_mfma<1><<<dim3(BCHN, NN/32), 256, 0, stream>>>(HpT, s_v, d_v, bmg, XB);
  proj2_mfma<<<dim3(NN/32, BCHN), 256, 0, stream>>>(XB, w2T, as2, ad2, HpT, s_v, d_v);
  attn_mfma<2><<<dim3(BCHN, NN/32), 256, 0, stream>>>(HpT, s_v, d_v, bmg, XB);
  reduce_heads<<<dim3(1024), 256, 0, stream>>>(XB, (float*)d_out);
}